// Round 18
// baseline (137.771 us; speedup 1.0000x reference)
//
#include <hip/hip_runtime.h>
#include <math.h>

#define M_TOTAL 35642          // bs * nq
#define NQ_ 17821
#define NV_ 17821
#define EMB 256
#define KDIM 256
#define QB 8
#define BM 64
#define BN 64
#define NTILES 10              // 640 / 64
#define MTILES ((M_TOTAL + BM - 1) / BM)   // 557

// ---- workspace layout (bytes) ----
#define WS_VAL_OFF   0ull
#define WS_VAL_BYTES (2ull * M_TOTAL * EMB)        // f16 value, head-major [2][8][NV_][32]
#define WS_OFFW_OFF  (WS_VAL_OFF + WS_VAL_BYTES)
#define WS_OFFW_BYTES (2ull * M_TOTAL * EMB)       // f16 off  [m][256]
#define WS_ATT_OFF   (WS_OFFW_OFF + WS_OFFW_BYTES)
#define WS_ATT_BYTES (2ull * M_TOTAL * 128)        // f16 attn logits [m][128]
#define WS_SAMP_OFF  (WS_ATT_OFF + WS_ATT_BYTES)   // 45,621,760
#define WS_SAMP_BYTES (2ull * M_TOTAL * EMB)       // f16 samp [m][256]
#define WS_NEED2     (WS_SAMP_OFF + WS_SAMP_BYTES) // 63,870,464 B (proven fits)
// WH (f16 [640][256], 327,680 B) OVERLAYS the samp region (disjoint lifetimes).
#define WS_WH_OFF    WS_SAMP_OFF

using f16x8 = __attribute__((ext_vector_type(8))) _Float16;
using f32x4 = __attribute__((ext_vector_type(4))) float;
typedef _Float16 h2 __attribute__((ext_vector_type(2)));

__device__ __forceinline__ unsigned short f2h(float f) {
  union { _Float16 h; unsigned short u; } v; v.h = (_Float16)f; return v.u;
}

// Async 16B global->LDS copy. LDS dest is WAVE-UNIFORM base; HW places each
// lane at base + lane*16 (m104/m108). Global source is per-lane, so swizzled
// LDS layouts are achieved by pre-swizzling the SOURCE address (m173).
__device__ __forceinline__ void async_cp16(const void* g, void* l) {
  __builtin_amdgcn_global_load_lds(
      (const __attribute__((address_space(1))) unsigned int*)g,
      (__attribute__((address_space(3))) unsigned int*)l, 16, 0, 0);
}

// Bijective XCD-aware block swizzle (m204 variant).
template <int NWG>
__device__ __forceinline__ int xcd_swz(int bid) {
  constexpr int q8 = NWG >> 3;
  constexpr int r8 = NWG & 7;
  const int xcd = bid & 7, idx = bid >> 3;
  return (xcd < r8 ? xcd * (q8 + 1) : r8 * (q8 + 1) + (xcd - r8) * q8) + idx;
}

// ---- k_prep: weights f32 -> f16 [640][256] ----
__global__ __launch_bounds__(256) void k_prep(
    const float* __restrict__ Wv, const float* __restrict__ Woff,
    const float* __restrict__ Wattn, _Float16* __restrict__ WH) {
  const int i = blockIdx.x * 256 + threadIdx.x;   // 8 elems each
  if (i >= 640 * 256 / 8) return;
  const int e   = i * 8;
  const int row = e >> 8;
  const int col = e & 255;
  const float* src = (row < 256) ? (Wv + (size_t)row * 256)
                   : (row < 512) ? (Woff + (size_t)(row - 256) * 256)
                                 : (Wattn + (size_t)(row - 512) * 256);
  const float4 a = *reinterpret_cast<const float4*>(src + col);
  const float4 b = *reinterpret_cast<const float4*>(src + col + 4);
  union { _Float16 h[8]; uint4 u; } p;
  p.h[0] = (_Float16)a.x; p.h[1] = (_Float16)a.y; p.h[2] = (_Float16)a.z; p.h[3] = (_Float16)a.w;
  p.h[4] = (_Float16)b.x; p.h[5] = (_Float16)b.y; p.h[6] = (_Float16)b.z; p.h[7] = (_Float16)b.w;
  *reinterpret_cast<uint4*>(WH + e) = p.u;
}

// ---- k_gemm1: grid = MTILES*2; each block: one M-tile x 5 N-tiles ----
__global__ __launch_bounds__(256) void k_gemm1(
    const float* __restrict__ Q,
    const _Float16* __restrict__ WH,
    const float* __restrict__ bv, const float* __restrict__ boff,
    const float* __restrict__ battn,
    unsigned short* __restrict__ valH,
    unsigned short* __restrict__ offH,
    unsigned short* __restrict__ attH) {

  __shared__ _Float16 Sh[BM * 256];   // 32 KB: A, then B per tile, then epilogue

  const int t = threadIdx.x;
  const int lane = t & 63;
  const int wid = t >> 6;
  const int wr = wid >> 1, wc = wid & 1;
  const int swz = xcd_swz<MTILES * 2>(blockIdx.x);   // pairs (mt,ng) share Q rows -> same XCD
  const int mt = swz >> 1;
  const int ng = swz & 1;             // N-tile group: nt = ng*5 .. ng*5+4
  const int mb = mt * BM;

  // ---- stage A (Q rows, f32->f16 cvt, manual; 16B-chunk XOR swizzle) ----
#pragma unroll
  for (int i = 0; i < 16; ++i) {
    const int g    = i * 256 + t;
    const int row  = g >> 6;
    const int c4   = g & 63;
    const int c8   = c4 >> 1;
    const int half = c4 & 1;
    const int eo   = row * 256 + ((c8 ^ (row & 7)) * 8) + half * 4;
    int ar = mb + row; if (ar > M_TOTAL - 1) ar = M_TOTAL - 1;
    const float4 qa = *reinterpret_cast<const float4*>(Q + (size_t)ar * KDIM + c4 * 4);
    union { _Float16 h[4]; uint2 u; } p;
    p.h[0] = (_Float16)qa.x; p.h[1] = (_Float16)qa.y;
    p.h[2] = (_Float16)qa.z; p.h[3] = (_Float16)qa.w;
    *reinterpret_cast<uint2*>(&Sh[eo]) = p.u;
  }
  __syncthreads();

  // ---- A-frags (full K) to registers: 16 x f16x8 = 64 VGPR ----
  f16x8 af[8][2];
#pragma unroll
  for (int kk = 0; kk < 8; ++kk)
#pragma unroll
    for (int f = 0; f < 2; ++f) {
      const int arow = wr * 32 + f * 16 + (lane & 15);
      const int ac   = (kk * 4 + (lane >> 4)) ^ (arow & 7);
      af[kk][f] = *reinterpret_cast<f16x8*>(&Sh[arow * 256 + ac * 8]);
    }
  __syncthreads();   // frag reads complete before B overwrites Sh

  for (int nti = 0; nti < 5; ++nti) {
    const int nt = ng * 5 + nti;
    const int nb = nt * BN;
    // ---- stage B tile: async global->LDS, pre-swizzled SOURCE, linear dest ----
#pragma unroll
    for (int i = 0; i < 8; ++i) {
      const int g   = i * 256 + t;
      const int row = g >> 5;
      const int c8s = (g & 31) ^ (row & 7);
      async_cp16(WH + (size_t)(nb + row) * 256 + c8s * 8,
                 &Sh[(i * 256 + wid * 64) * 8]);
    }
    __syncthreads();   // drains vmcnt

    f32x4 acc[2][2];
#pragma unroll
    for (int a = 0; a < 2; ++a)
#pragma unroll
      for (int b = 0; b < 2; ++b) acc[a][b] = (f32x4)0.f;

#pragma unroll
    for (int kk = 0; kk < 8; ++kk) {
      f16x8 bf[2];
#pragma unroll
      for (int f = 0; f < 2; ++f) {
        const int brow = wc * 32 + f * 16 + (lane & 15);
        const int bc   = (kk * 4 + (lane >> 4)) ^ (brow & 7);
        bf[f] = *reinterpret_cast<f16x8*>(&Sh[brow * 256 + bc * 8]);
      }
#pragma unroll
      for (int fr = 0; fr < 2; ++fr)
#pragma unroll
        for (int fc = 0; fc < 2; ++fc)
          acc[fr][fc] = __builtin_amdgcn_mfma_f32_16x16x32_f16(af[kk][fr], bf[fc], acc[fr][fc], 0, 0, 0);
    }
    __syncthreads();   // MFMA's LDS reads done; Sh reusable for epilogue

    // ---- epilogue: acc+bias -> f16 LDS tile [64][64], then coalesced 16B stores ----
    {
      const float* bsec; int nsb;
      if (nt < 4)      { bsec = bv;    nsb = 0;   }
      else if (nt < 8) { bsec = boff;  nsb = 256; }
      else             { bsec = battn; nsb = 512; }
      const int nrow0 = nb - nsb;
      const int col = lane & 15;
      const int rg4 = lane >> 4;
      float bias2[2];
      bias2[0] = bsec[nrow0 + wc * 32 + 0 * 16 + col];
      bias2[1] = bsec[nrow0 + wc * 32 + 1 * 16 + col];
      unsigned short* Ep = reinterpret_cast<unsigned short*>(Sh);   // [64][64] u16 (8 KB)
#pragma unroll
      for (int fr = 0; fr < 2; ++fr)
#pragma unroll
        for (int fc = 0; fc < 2; ++fc)
#pragma unroll
          for (int j = 0; j < 4; ++j)
            Ep[(wr * 32 + fr * 16 + rg4 * 4 + j) * 64 + wc * 32 + fc * 16 + col] =
                f2h(acc[fr][fc][j] + bias2[fc]);
      __syncthreads();

      // 64 rows x 8 chunks(16B) = 512 chunks; thread handles 2
#pragma unroll
      for (int i = 0; i < 2; ++i) {
        const int g   = i * 256 + t;
        const int row = g >> 3;
        const int ch  = g & 7;
        const int m   = mb + row;
        if (m < M_TOTAL) {
          const uint4 v = *reinterpret_cast<const uint4*>(&Ep[row * 64 + ch * 8]);
          const int n0 = nb + ch * 8;
          if (nsb == 0) {
            const int b  = (m >= NQ_) ? 1 : 0;
            const int mm = m - b * NQ_;
            *reinterpret_cast<uint4*>(&valH[((size_t)(b * 8 + (n0 >> 5)) * NV_ + mm) * 32 + (n0 & 31)]) = v;
          } else if (nsb == 256) {
            *reinterpret_cast<uint4*>(&offH[(size_t)m * 256 + (n0 - 256)]) = v;
          } else {
            *reinterpret_cast<uint4*>(&attH[(size_t)m * 128 + (n0 - 512)]) = v;
          }
        }
      }
    }
    __syncthreads();   // epilogue reads done before next tile's B-stage
  }
}

// ---- k_gather: softmax + bilinear gather -> f16 samp ws ----
// r13 mapping (q,h,dq in 0..3) + POINT-PAIR load pipelining: both points'
// 8 corner loads issue back-to-back before either FMA block -> 2x memory-
// level parallelism. Predicted VGPR ~56-64 (64 is the 8-waves/SIMD
// boundary; r10's 188 / r14's 132 crossed it and regressed).
__global__ __launch_bounds__(256) void k_gather(
    const float* __restrict__ refp,
    const unsigned short* __restrict__ valH,
    const unsigned short* __restrict__ offH,
    const unsigned short* __restrict__ attH,
    unsigned short* __restrict__ sampH) {

  const int t  = threadIdx.x;
  const int q0 = xcd_swz<(M_TOTAL + QB - 1) / QB>(blockIdx.x) * QB;
  const int q  = t >> 5;
  const int h  = (t >> 2) & 7;
  const int dq = t & 3;
  const int m  = q0 + q;
  const int mc = min(m, M_TOTAL - 1);

  // softmax over f16 logits
  float aw[16];
  {
    const f16x8 a0 = *reinterpret_cast<const f16x8*>(attH + (size_t)mc * 128 + h * 16);
    const f16x8 a1 = *reinterpret_cast<const f16x8*>(attH + (size_t)mc * 128 + h * 16 + 8);
#pragma unroll
    for (int i = 0; i < 8; ++i) { aw[i] = (float)a0[i]; aw[8 + i] = (float)a1[i]; }
  }
  float mx = aw[0];
#pragma unroll
  for (int i = 1; i < 16; ++i) mx = fmaxf(mx, aw[i]);
  float ssum = 0.f;
#pragma unroll
  for (int i = 0; i < 16; ++i) { aw[i] = __expf(aw[i] - mx); ssum += aw[i]; }
  const float inv = 1.0f / ssum;
#pragma unroll
  for (int i = 0; i < 16; ++i) aw[i] *= inv;

  h2 sacc2[4];
#pragma unroll
  for (int j = 0; j < 4; ++j) { sacc2[j][0] = (_Float16)0.f; sacc2[j][1] = (_Float16)0.f; }

  {
    constexpr int LH[4] = {100, 50, 25, 13};
    constexpr int LW[4] = {134, 67, 34, 17};
    constexpr int LS[4] = {0, 13400, 16750, 17600};
    const int b = (mc >= NQ_) ? 1 : 0;
    const float* rp = refp + (size_t)mc * 8;
    const uint4* vb = reinterpret_cast<const uint4*>(valH) + (size_t)(b * 8 + h) * NV_ * 4 + dq;

#pragma unroll
    for (int lvl = 0; lvl < 4; ++lvl) {
      const int Hl = LH[lvl], Wl = LW[lvl], st = LS[lvl];
      const float Hf = (float)Hl, Wf = (float)Wl;
      const float2 rxy = *reinterpret_cast<const float2*>(rp + lvl * 2);
      const f16x8 ov = *reinterpret_cast<const f16x8*>(offH + (size_t)mc * 256 + h * 32 + lvl * 8);
#pragma unroll
      for (int pp = 0; pp < 2; ++pp) {      // point PAIR: p = 2*pp, 2*pp+1
        h2 wq[2][4];
        size_t idx[2][4];
#pragma unroll
        for (int s = 0; s < 2; ++s) {
          const int p = pp * 2 + s;
          const float ox = (float)ov[p * 2 + 0];
          const float oy = (float)ov[p * 2 + 1];
          // (rx + ox/W)*W - 0.5 == rx*W + ox - 0.5 up to ~1 ulp (r10-verified)
          const float x = fmaf(rxy.x, Wf, ox) - 0.5f;
          const float y = fmaf(rxy.y, Hf, oy) - 0.5f;
          const float xf = floorf(x), yf = floorf(y);
          const float wx = x - xf, wy = y - yf;
          const int x0i = (int)xf, y0i = (int)yf;
          const int x1i = x0i + 1, y1i = y0i + 1;
          const float vx0 = (x0i >= 0 && x0i < Wl) ? 1.f : 0.f;
          const float vx1 = (x1i >= 0 && x1i < Wl) ? 1.f : 0.f;
          const float vy0 = (y0i >= 0 && y0i < Hl) ? 1.f : 0.f;
          const float vy1 = (y1i >= 0 && y1i < Hl) ? 1.f : 0.f;
          const int x0c = min(max(x0i, 0), Wl - 1);
          const int x1c = min(max(x1i, 0), Wl - 1);
          const int y0c = min(max(y0i, 0), Hl - 1);
          const int y1c = min(max(y1i, 0), Hl - 1);
          const float a = aw[lvl * 4 + p];
          const float w00 = a * (1.f - wy) * (1.f - wx) * (vy0 * vx0);
          const float w01 = a * (1.f - wy) * wx         * (vy0 * vx1);
          const float w10 = a * wy         * (1.f - wx) * (vy1 * vx0);
          const float w11 = a * wy         * wx         * (vy1 * vx1);
          const _Float16 h00 = (_Float16)w00, h01 = (_Float16)w01;
          const _Float16 h10 = (_Float16)w10, h11 = (_Float16)w11;
          wq[s][0] = h2{h00, h00};
          wq[s][1] = h2{h01, h01};
          wq[s][2] = h2{h10, h10};
          wq[s][3] = h2{h11, h11};
          idx[s][0] = (size_t)(st + y0c * Wl + x0c) * 4;
          idx[s][1] = (size_t)(st + y0c * Wl + x1c) * 4;
          idx[s][2] = (size_t)(st + y1c * Wl + x0c) * 4;
          idx[s][3] = (size_t)(st + y1c * Wl + x1c) * 4;
        }
        // issue all 8 corner loads back-to-back (2x outstanding vs 1-point form)
        union UV { uint4 u; h2 hh[4]; };
        UV c[2][4];
#pragma unroll
        for (int s = 0; s < 2; ++s)
#pragma unroll
          for (int k = 0; k < 4; ++k) c[s][k].u = vb[idx[s][k]];
#pragma unroll
        for (int s = 0; s < 2; ++s)
#pragma unroll
          for (int k = 0; k < 4; ++k)
#pragma unroll
            for (int j = 0; j < 4; ++j)
              sacc2[j] += c[s][k].hh[j] * wq[s][k];
      }
    }
  }

  if (m < M_TOTAL) {
    union { h2 hh[4]; uint4 u; } pk;
#pragma unroll
    for (int j = 0; j < 4; ++j) pk.hh[j] = sacc2[j];
    *reinterpret_cast<uint4*>(sampH + (size_t)m * 256 + h * 32 + dq * 8) = pk.u;
  }
}

// ---- k_gemm2: out = samp @ Wout^T + bout + Q (residual), MFMA ----
__global__ __launch_bounds__(256) void k_gemm2(
    const float* __restrict__ Q,
    const unsigned short* __restrict__ sampH,   // f16 bits [m][256]
    const float* __restrict__ Wout, const float* __restrict__ bout,
    float* __restrict__ out) {

  __shared__ _Float16 As[BM * 128];
  __shared__ _Float16 Bs[BN * 128];

  const int swz = xcd_swz<MTILES * 4>(blockIdx.x);  // 4 same-A blocks -> same XCD
  const int nt = swz & 3;
  const int mt = swz >> 2;
  const int t = threadIdx.x;
  const int lane = t & 63;
  const int wid = t >> 6;
  const int wr = wid >> 1, wc = wid & 1;
  const int mb = mt * BM;
  const int nb = nt * BN;

  f32x4 acc[2][2];
#pragma unroll
  for (int a = 0; a < 2; ++a)
#pragma unroll
    for (int b = 0; b < 2; ++b) acc[a][b] = (f32x4)0.f;

  for (int kc = 0; kc < 2; ++kc) {
    const int koff = kc * 128;
    // ---- stage A (sampH, f16 pure copy): async, pre-swizzled source ----
#pragma unroll
    for (int i = 0; i < 4; ++i) {
      const int g   = i * 256 + t;
      const int row = g >> 4;
      const int c8s = (g & 15) ^ (row & 7);
      int ar = mb + row; if (ar > M_TOTAL - 1) ar = M_TOTAL - 1;
      async_cp16(sampH + (size_t)ar * 256 + koff + c8s * 8,
                 &As[(i * 256 + wid * 64) * 8]);
    }
    // ---- stage B (Wout, needs f32->f16 cvt): manual ----
#pragma unroll
    for (int i = 0; i < 4; ++i) {
      const int g   = i * 256 + t;
      const int row = g >> 4;
      const int c8  = g & 15;
      const int eo  = row * 128 + (c8 ^ (row & 7)) * 8;
      const float4 w0 = *reinterpret_cast<const float4*>(Wout + (size_t)(nb + row) * KDIM + koff + c8 * 8);
      const float4 w1 = *reinterpret_cast<const float4*>(Wout + (size_t)(nb + row) * KDIM + koff + c8 * 8 + 4);
      union { _Float16 h[8]; uint4 u; } pb;
      pb.h[0] = (_Float16)w0.x; pb.h[1] = (_Float16)w0.y;
      pb.h[2] = (_Float16)w0.z; pb.h[3] = (_Float16)w0.w;
      pb.h[4] = (_Float16)w1.x; pb.h[5] = (_Float16)w1.y;
      pb.h[6] = (_Float16)w1.z; pb.h[7] = (_Float16)w1.w;
      *reinterpret_cast<uint4*>(&Bs[eo]) = pb.u;
    }
    __syncthreads();   // drains vmcnt + lgkmcnt

#pragma unroll
    for (int kk = 0; kk < 4; ++kk) {
      f16x8 af[2], bf[2];
#pragma unroll
      for (int f = 0; f < 2; ++f) {
        const int arow = wr * 32 + f * 16 + (lane & 15);
        const int ac   = (kk * 4 + (lane >> 4)) ^ (arow & 7);
        af[f] = *reinterpret_cast<f16x8*>(&As[arow * 128 + ac * 8]);
        const int brow = wc * 32 + f * 16 + (lane & 15);
        const int bc   = (kk * 4 + (lane >> 4)) ^ (brow & 7);
        bf[f] = *reinterpret_cast<f16x8*>(&Bs[brow * 128 + bc * 8]);
      }
#pragma unroll
      for (int fr = 0; fr < 2; ++fr)
#pragma unroll
        for (int fc = 0; fc < 2; ++fc)
          acc[fr][fc] = __builtin_amdgcn_mfma_f32_16x16x32_f16(af[fr], bf[fc], acc[fr][fc], 0, 0, 0);
    }
    __syncthreads();
  }

  // ---- epilogue: acc+bias -> f32 LDS tile [64][64] (in As, 16 KB), then
  //      coalesced float4 Q-load + add + float4 store ----
  {
    const int col = lane & 15;
    const int rg4 = lane >> 4;
    float bias2[2];
    bias2[0] = bout[nb + wc * 32 + 0 * 16 + col];
    bias2[1] = bout[nb + wc * 32 + 1 * 16 + col];
    float* Ep = reinterpret_cast<float*>(As);   // [64][64] f32 = 16 KB exact
#pragma unroll
    for (int fr = 0; fr < 2; ++fr)
#pragma unroll
      for (int fc = 0; fc < 2; ++fc)
#pragma unroll
        for (int j = 0; j < 4; ++j)
          Ep[(wr * 32 + fr * 16 + rg4 * 4 + j) * 64 + wc * 32 + fc * 16 + col] =
              acc[fr][fc][j] + bias2[fc];
    __syncthreads();

    // 64 rows x 16 chunks(16B) = 1024 chunks; thread handles 4
#pragma unroll
    for (int i = 0; i < 4; ++i) {
      const int g   = i * 256 + t;
      const int row = g >> 4;
      const int ch  = g & 15;
      const int m   = mb + row;
      if (m < M_TOTAL) {
        const int n0 = nb + ch * 4;
        float4 v = *reinterpret_cast<const float4*>(&Ep[row * 64 + ch * 4]);
        const float4 q4 = *reinterpret_cast<const float4*>(Q + (size_t)m * EMB + n0);
        v.x += q4.x; v.y += q4.y; v.z += q4.z; v.w += q4.w;
        *reinterpret_cast<float4*>(out + (size_t)m * EMB + n0) = v;
      }
    }
  }
}

extern "C" void kernel_launch(void* const* d_in, const int* in_sizes, int n_in,
                              void* d_out, int out_size, void* d_ws, size_t ws_size,
                              hipStream_t stream) {
  const float* Q     = (const float*)d_in[0];
  const float* refp  = (const float*)d_in[1];
  const float* Wv    = (const float*)d_in[3];
  const float* bv    = (const float*)d_in[4];
  const float* Woff  = (const float*)d_in[5];
  const float* boff  = (const float*)d_in[6];
  const float* Wattn = (const float*)d_in[7];
  const float* battn = (const float*)d_in[8];
  const float* Wout  = (const float*)d_in[9];
  const float* bout  = (const float*)d_in[10];
  float* out = (float*)d_out;

  if (ws_size < WS_NEED2) return;

  unsigned short* valH  = (unsigned short*)((char*)d_ws + WS_VAL_OFF);
  unsigned short* offH  = (unsigned short*)((char*)d_ws + WS_OFFW_OFF);
  unsigned short* attH  = (unsigned short*)((char*)d_ws + WS_ATT_OFF);
  unsigned short* sampH = (unsigned short*)((char*)d_ws + WS_SAMP_OFF);
  _Float16*       WH    = (_Float16*)((char*)d_ws + WS_WH_OFF);   // overlays sampH

  const int nblk_q8 = (M_TOTAL + QB - 1) / QB;   // 4456

  k_prep<<<dim3(80), dim3(256), 0, stream>>>(Wv, Woff, Wattn, WH);
  k_gemm1<<<dim3(MTILES * 2), dim3(256), 0, stream>>>(Q, WH, bv, boff, battn,
                                                      valH, offH, attH);
  k_gather<<<dim3(nblk_q8), dim3(256), 0, stream>>>(refp, valH, offH, attH, sampH);
  k_gemm2<<<dim3(MTILES * 4), dim3(256), 0, stream>>>(Q, sampH, Wout, bout, out);
}

// Round 19
// 135.408 us; speedup vs baseline: 1.0174x; 1.0174x over previous
//
#include <hip/hip_runtime.h>
#include <math.h>

#define M_TOTAL 35642          // bs * nq
#define NQ_ 17821
#define NV_ 17821
#define EMB 256
#define KDIM 256
#define QB 8
#define BM 64
#define BN 64
#define NTILES 10              // 640 / 64
#define MTILES ((M_TOTAL + BM - 1) / BM)   // 557

// ---- workspace layout (bytes) ----
#define WS_VAL_OFF   0ull
#define WS_VAL_BYTES (2ull * M_TOTAL * EMB)        // f16 value, head-major [2][8][NV_][32]
#define WS_OFFW_OFF  (WS_VAL_OFF + WS_VAL_BYTES)
#define WS_OFFW_BYTES (2ull * M_TOTAL * EMB)       // f16 off  [m][256]
#define WS_ATT_OFF   (WS_OFFW_OFF + WS_OFFW_BYTES)
#define WS_ATT_BYTES (2ull * M_TOTAL * 128)        // f16 attn logits [m][128]
#define WS_SAMP_OFF  (WS_ATT_OFF + WS_ATT_BYTES)   // 45,621,760
#define WS_SAMP_BYTES (2ull * M_TOTAL * EMB)       // f16 samp [m][256]
#define WS_NEED2     (WS_SAMP_OFF + WS_SAMP_BYTES) // 63,870,464 B (proven fits)
// WH (f16 [640][256], 327,680 B) OVERLAYS the samp region (disjoint lifetimes).
#define WS_WH_OFF    WS_SAMP_OFF

using f16x8 = __attribute__((ext_vector_type(8))) _Float16;
using f32x4 = __attribute__((ext_vector_type(4))) float;
typedef _Float16 h2 __attribute__((ext_vector_type(2)));

__device__ __forceinline__ unsigned short f2h(float f) {
  union { _Float16 h; unsigned short u; } v; v.h = (_Float16)f; return v.u;
}

// Async 16B global->LDS copy. LDS dest is WAVE-UNIFORM base; HW places each
// lane at base + lane*16 (m104/m108). Global source is per-lane, so swizzled
// LDS layouts are achieved by pre-swizzling the SOURCE address (m173).
__device__ __forceinline__ void async_cp16(const void* g, void* l) {
  __builtin_amdgcn_global_load_lds(
      (const __attribute__((address_space(1))) unsigned int*)g,
      (__attribute__((address_space(3))) unsigned int*)l, 16, 0, 0);
}

// Bijective XCD-aware block swizzle (m204 variant).
template <int NWG>
__device__ __forceinline__ int xcd_swz(int bid) {
  constexpr int q8 = NWG >> 3;
  constexpr int r8 = NWG & 7;
  const int xcd = bid & 7, idx = bid >> 3;
  return (xcd < r8 ? xcd * (q8 + 1) : r8 * (q8 + 1) + (xcd - r8) * q8) + idx;
}

// ---- k_prep: weights f32 -> f16 [640][256] ----
__global__ __launch_bounds__(256) void k_prep(
    const float* __restrict__ Wv, const float* __restrict__ Woff,
    const float* __restrict__ Wattn, _Float16* __restrict__ WH) {
  const int i = blockIdx.x * 256 + threadIdx.x;   // 8 elems each
  if (i >= 640 * 256 / 8) return;
  const int e   = i * 8;
  const int row = e >> 8;
  const int col = e & 255;
  const float* src = (row < 256) ? (Wv + (size_t)row * 256)
                   : (row < 512) ? (Woff + (size_t)(row - 256) * 256)
                                 : (Wattn + (size_t)(row - 512) * 256);
  const float4 a = *reinterpret_cast<const float4*>(src + col);
  const float4 b = *reinterpret_cast<const float4*>(src + col + 4);
  union { _Float16 h[8]; uint4 u; } p;
  p.h[0] = (_Float16)a.x; p.h[1] = (_Float16)a.y; p.h[2] = (_Float16)a.z; p.h[3] = (_Float16)a.w;
  p.h[4] = (_Float16)b.x; p.h[5] = (_Float16)b.y; p.h[6] = (_Float16)b.z; p.h[7] = (_Float16)b.w;
  *reinterpret_cast<uint4*>(WH + e) = p.u;
}

// ---- k_gemm1: grid = MTILES*2; each block: one M-tile x 5 N-tiles ----
__global__ __launch_bounds__(256) void k_gemm1(
    const float* __restrict__ Q,
    const _Float16* __restrict__ WH,
    const float* __restrict__ bv, const float* __restrict__ boff,
    const float* __restrict__ battn,
    unsigned short* __restrict__ valH,
    unsigned short* __restrict__ offH,
    unsigned short* __restrict__ attH) {

  __shared__ _Float16 Sh[BM * 256];   // 32 KB: A, then B per tile, then epilogue

  const int t = threadIdx.x;
  const int lane = t & 63;
  const int wid = t >> 6;
  const int wr = wid >> 1, wc = wid & 1;
  const int swz = xcd_swz<MTILES * 2>(blockIdx.x);   // pairs (mt,ng) share Q rows -> same XCD
  const int mt = swz >> 1;
  const int ng = swz & 1;             // N-tile group: nt = ng*5 .. ng*5+4
  const int mb = mt * BM;

  // ---- stage A (Q rows, f32->f16 cvt, manual; 16B-chunk XOR swizzle) ----
#pragma unroll
  for (int i = 0; i < 16; ++i) {
    const int g    = i * 256 + t;
    const int row  = g >> 6;
    const int c4   = g & 63;
    const int c8   = c4 >> 1;
    const int half = c4 & 1;
    const int eo   = row * 256 + ((c8 ^ (row & 7)) * 8) + half * 4;
    int ar = mb + row; if (ar > M_TOTAL - 1) ar = M_TOTAL - 1;
    const float4 qa = *reinterpret_cast<const float4*>(Q + (size_t)ar * KDIM + c4 * 4);
    union { _Float16 h[4]; uint2 u; } p;
    p.h[0] = (_Float16)qa.x; p.h[1] = (_Float16)qa.y;
    p.h[2] = (_Float16)qa.z; p.h[3] = (_Float16)qa.w;
    *reinterpret_cast<uint2*>(&Sh[eo]) = p.u;
  }
  __syncthreads();

  // ---- A-frags (full K) to registers: 16 x f16x8 = 64 VGPR ----
  f16x8 af[8][2];
#pragma unroll
  for (int kk = 0; kk < 8; ++kk)
#pragma unroll
    for (int f = 0; f < 2; ++f) {
      const int arow = wr * 32 + f * 16 + (lane & 15);
      const int ac   = (kk * 4 + (lane >> 4)) ^ (arow & 7);
      af[kk][f] = *reinterpret_cast<f16x8*>(&Sh[arow * 256 + ac * 8]);
    }
  __syncthreads();   // frag reads complete before B overwrites Sh

  for (int nti = 0; nti < 5; ++nti) {
    const int nt = ng * 5 + nti;
    const int nb = nt * BN;
    // ---- stage B tile: async global->LDS, pre-swizzled SOURCE, linear dest ----
#pragma unroll
    for (int i = 0; i < 8; ++i) {
      const int g   = i * 256 + t;
      const int row = g >> 5;
      const int c8s = (g & 31) ^ (row & 7);
      async_cp16(WH + (size_t)(nb + row) * 256 + c8s * 8,
                 &Sh[(i * 256 + wid * 64) * 8]);
    }
    __syncthreads();   // drains vmcnt

    f32x4 acc[2][2];
#pragma unroll
    for (int a = 0; a < 2; ++a)
#pragma unroll
      for (int b = 0; b < 2; ++b) acc[a][b] = (f32x4)0.f;

#pragma unroll
    for (int kk = 0; kk < 8; ++kk) {
      f16x8 bf[2];
#pragma unroll
      for (int f = 0; f < 2; ++f) {
        const int brow = wc * 32 + f * 16 + (lane & 15);
        const int bc   = (kk * 4 + (lane >> 4)) ^ (brow & 7);
        bf[f] = *reinterpret_cast<f16x8*>(&Sh[brow * 256 + bc * 8]);
      }
#pragma unroll
      for (int fr = 0; fr < 2; ++fr)
#pragma unroll
        for (int fc = 0; fc < 2; ++fc)
          acc[fr][fc] = __builtin_amdgcn_mfma_f32_16x16x32_f16(af[kk][fr], bf[fc], acc[fr][fc], 0, 0, 0);
    }
    __syncthreads();   // MFMA's LDS reads done; Sh reusable for epilogue

    // ---- epilogue: acc+bias -> f16 LDS tile [64][64], then coalesced 16B stores ----
    {
      const float* bsec; int nsb;
      if (nt < 4)      { bsec = bv;    nsb = 0;   }
      else if (nt < 8) { bsec = boff;  nsb = 256; }
      else             { bsec = battn; nsb = 512; }
      const int nrow0 = nb - nsb;
      const int col = lane & 15;
      const int rg4 = lane >> 4;
      float bias2[2];
      bias2[0] = bsec[nrow0 + wc * 32 + 0 * 16 + col];
      bias2[1] = bsec[nrow0 + wc * 32 + 1 * 16 + col];
      unsigned short* Ep = reinterpret_cast<unsigned short*>(Sh);   // [64][64] u16 (8 KB)
#pragma unroll
      for (int fr = 0; fr < 2; ++fr)
#pragma unroll
        for (int fc = 0; fc < 2; ++fc)
#pragma unroll
          for (int j = 0; j < 4; ++j)
            Ep[(wr * 32 + fr * 16 + rg4 * 4 + j) * 64 + wc * 32 + fc * 16 + col] =
                f2h(acc[fr][fc][j] + bias2[fc]);
      __syncthreads();

      // 64 rows x 8 chunks(16B) = 512 chunks; thread handles 2
#pragma unroll
      for (int i = 0; i < 2; ++i) {
        const int g   = i * 256 + t;
        const int row = g >> 3;
        const int ch  = g & 7;
        const int m   = mb + row;
        if (m < M_TOTAL) {
          const uint4 v = *reinterpret_cast<const uint4*>(&Ep[row * 64 + ch * 8]);
          const int n0 = nb + ch * 8;
          if (nsb == 0) {
            const int b  = (m >= NQ_) ? 1 : 0;
            const int mm = m - b * NQ_;
            *reinterpret_cast<uint4*>(&valH[((size_t)(b * 8 + (n0 >> 5)) * NV_ + mm) * 32 + (n0 & 31)]) = v;
          } else if (nsb == 256) {
            *reinterpret_cast<uint4*>(&offH[(size_t)m * 256 + (n0 - 256)]) = v;
          } else {
            *reinterpret_cast<uint4*>(&attH[(size_t)m * 128 + (n0 - 512)]) = v;
          }
        }
      }
    }
    __syncthreads();   // epilogue reads done before next tile's B-stage
  }
}

// ---- k_gather: softmax + bilinear gather -> f16 samp ws ----
// r13 mapping (q,h,dq in 0..3) + point-pair structure + T19
// sched_group_barrier pinning [addr VALU][8 clustered VMEM][FMA VALU].
// r18 showed source pairing alone is re-serialized by the scheduler
// (VGPR stayed 40); SGB is the compile-time directive that pins it.
__global__ __launch_bounds__(256) void k_gather(
    const float* __restrict__ refp,
    const unsigned short* __restrict__ valH,
    const unsigned short* __restrict__ offH,
    const unsigned short* __restrict__ attH,
    unsigned short* __restrict__ sampH) {

  const int t  = threadIdx.x;
  const int q0 = xcd_swz<(M_TOTAL + QB - 1) / QB>(blockIdx.x) * QB;
  const int q  = t >> 5;
  const int h  = (t >> 2) & 7;
  const int dq = t & 3;
  const int m  = q0 + q;
  const int mc = min(m, M_TOTAL - 1);

  // softmax over f16 logits
  float aw[16];
  {
    const f16x8 a0 = *reinterpret_cast<const f16x8*>(attH + (size_t)mc * 128 + h * 16);
    const f16x8 a1 = *reinterpret_cast<const f16x8*>(attH + (size_t)mc * 128 + h * 16 + 8);
#pragma unroll
    for (int i = 0; i < 8; ++i) { aw[i] = (float)a0[i]; aw[8 + i] = (float)a1[i]; }
  }
  float mx = aw[0];
#pragma unroll
  for (int i = 1; i < 16; ++i) mx = fmaxf(mx, aw[i]);
  float ssum = 0.f;
#pragma unroll
  for (int i = 0; i < 16; ++i) { aw[i] = __expf(aw[i] - mx); ssum += aw[i]; }
  const float inv = 1.0f / ssum;
#pragma unroll
  for (int i = 0; i < 16; ++i) aw[i] *= inv;

  h2 sacc2[4];
#pragma unroll
  for (int j = 0; j < 4; ++j) { sacc2[j][0] = (_Float16)0.f; sacc2[j][1] = (_Float16)0.f; }

  {
    constexpr int LH[4] = {100, 50, 25, 13};
    constexpr int LW[4] = {134, 67, 34, 17};
    constexpr int LS[4] = {0, 13400, 16750, 17600};
    const int b = (mc >= NQ_) ? 1 : 0;
    const float* rp = refp + (size_t)mc * 8;
    const uint4* vb = reinterpret_cast<const uint4*>(valH) + (size_t)(b * 8 + h) * NV_ * 4 + dq;

#pragma unroll
    for (int lvl = 0; lvl < 4; ++lvl) {
      const int Hl = LH[lvl], Wl = LW[lvl], st = LS[lvl];
      const float Hf = (float)Hl, Wf = (float)Wl;
      const float2 rxy = *reinterpret_cast<const float2*>(rp + lvl * 2);
      const f16x8 ov = *reinterpret_cast<const f16x8*>(offH + (size_t)mc * 256 + h * 32 + lvl * 8);
#pragma unroll
      for (int pp = 0; pp < 2; ++pp) {      // point PAIR: p = 2*pp, 2*pp+1
        h2 wq[2][4];
        size_t idx[2][4];
#pragma unroll
        for (int s = 0; s < 2; ++s) {
          const int p = pp * 2 + s;
          const float ox = (float)ov[p * 2 + 0];
          const float oy = (float)ov[p * 2 + 1];
          // (rx + ox/W)*W - 0.5 == rx*W + ox - 0.5 up to ~1 ulp (r10-verified)
          const float x = fmaf(rxy.x, Wf, ox) - 0.5f;
          const float y = fmaf(rxy.y, Hf, oy) - 0.5f;
          const float xf = floorf(x), yf = floorf(y);
          const float wx = x - xf, wy = y - yf;
          const int x0i = (int)xf, y0i = (int)yf;
          const int x1i = x0i + 1, y1i = y0i + 1;
          const float vx0 = (x0i >= 0 && x0i < Wl) ? 1.f : 0.f;
          const float vx1 = (x1i >= 0 && x1i < Wl) ? 1.f : 0.f;
          const float vy0 = (y0i >= 0 && y0i < Hl) ? 1.f : 0.f;
          const float vy1 = (y1i >= 0 && y1i < Hl) ? 1.f : 0.f;
          const int x0c = min(max(x0i, 0), Wl - 1);
          const int x1c = min(max(x1i, 0), Wl - 1);
          const int y0c = min(max(y0i, 0), Hl - 1);
          const int y1c = min(max(y1i, 0), Hl - 1);
          const float a = aw[lvl * 4 + p];
          const float w00 = a * (1.f - wy) * (1.f - wx) * (vy0 * vx0);
          const float w01 = a * (1.f - wy) * wx         * (vy0 * vx1);
          const float w10 = a * wy         * (1.f - wx) * (vy1 * vx0);
          const float w11 = a * wy         * wx         * (vy1 * vx1);
          const _Float16 h00 = (_Float16)w00, h01 = (_Float16)w01;
          const _Float16 h10 = (_Float16)w10, h11 = (_Float16)w11;
          wq[s][0] = h2{h00, h00};
          wq[s][1] = h2{h01, h01};
          wq[s][2] = h2{h10, h10};
          wq[s][3] = h2{h11, h11};
          idx[s][0] = (size_t)(st + y0c * Wl + x0c) * 4;
          idx[s][1] = (size_t)(st + y0c * Wl + x1c) * 4;
          idx[s][2] = (size_t)(st + y1c * Wl + x0c) * 4;
          idx[s][3] = (size_t)(st + y1c * Wl + x1c) * 4;
        }
        // issue all 8 corner loads back-to-back
        union UV { uint4 u; h2 hh[4]; };
        UV c[2][4];
#pragma unroll
        for (int s = 0; s < 2; ++s)
#pragma unroll
          for (int k = 0; k < 4; ++k) c[s][k].u = vb[idx[s][k]];
#pragma unroll
        for (int s = 0; s < 2; ++s)
#pragma unroll
          for (int k = 0; k < 4; ++k)
#pragma unroll
            for (int j = 0; j < 4; ++j)
              sacc2[j] += c[s][k].hh[j] * wq[s][k];
        // T19: pin [addr/weight VALU][8 clustered VMEM reads][FMA VALU].
        // Masks per LLVM SchedGroupMask: VALU=0x2, VMEM_READ=0x20.
        __builtin_amdgcn_sched_group_barrier(0x002, 96, 0);
        __builtin_amdgcn_sched_group_barrier(0x020, 8, 0);
        __builtin_amdgcn_sched_group_barrier(0x002, 64, 0);
      }
    }
  }

  if (m < M_TOTAL) {
    union { h2 hh[4]; uint4 u; } pk;
#pragma unroll
    for (int j = 0; j < 4; ++j) pk.hh[j] = sacc2[j];
    *reinterpret_cast<uint4*>(sampH + (size_t)m * 256 + h * 32 + dq * 8) = pk.u;
  }
}

// ---- k_gemm2: out = samp @ Wout^T + bout + Q (residual), MFMA ----
__global__ __launch_bounds__(256) void k_gemm2(
    const float* __restrict__ Q,
    const unsigned short* __restrict__ sampH,   // f16 bits [m][256]
    const float* __restrict__ Wout, const float* __restrict__ bout,
    float* __restrict__ out) {

  __shared__ _Float16 As[BM * 128];
  __shared__ _Float16 Bs[BN * 128];

  const int swz = xcd_swz<MTILES * 4>(blockIdx.x);  // 4 same-A blocks -> same XCD
  const int nt = swz & 3;
  const int mt = swz >> 2;
  const int t = threadIdx.x;
  const int lane = t & 63;
  const int wid = t >> 6;
  const int wr = wid >> 1, wc = wid & 1;
  const int mb = mt * BM;
  const int nb = nt * BN;

  f32x4 acc[2][2];
#pragma unroll
  for (int a = 0; a < 2; ++a)
#pragma unroll
    for (int b = 0; b < 2; ++b) acc[a][b] = (f32x4)0.f;

  for (int kc = 0; kc < 2; ++kc) {
    const int koff = kc * 128;
    // ---- stage A (sampH, f16 pure copy): async, pre-swizzled source ----
#pragma unroll
    for (int i = 0; i < 4; ++i) {
      const int g   = i * 256 + t;
      const int row = g >> 4;
      const int c8s = (g & 15) ^ (row & 7);
      int ar = mb + row; if (ar > M_TOTAL - 1) ar = M_TOTAL - 1;
      async_cp16(sampH + (size_t)ar * 256 + koff + c8s * 8,
                 &As[(i * 256 + wid * 64) * 8]);
    }
    // ---- stage B (Wout, needs f32->f16 cvt): manual ----
#pragma unroll
    for (int i = 0; i < 4; ++i) {
      const int g   = i * 256 + t;
      const int row = g >> 4;
      const int c8  = g & 15;
      const int eo  = row * 128 + (c8 ^ (row & 7)) * 8;
      const float4 w0 = *reinterpret_cast<const float4*>(Wout + (size_t)(nb + row) * KDIM + koff + c8 * 8);
      const float4 w1 = *reinterpret_cast<const float4*>(Wout + (size_t)(nb + row) * KDIM + koff + c8 * 8 + 4);
      union { _Float16 h[8]; uint4 u; } pb;
      pb.h[0] = (_Float16)w0.x; pb.h[1] = (_Float16)w0.y;
      pb.h[2] = (_Float16)w0.z; pb.h[3] = (_Float16)w0.w;
      pb.h[4] = (_Float16)w1.x; pb.h[5] = (_Float16)w1.y;
      pb.h[6] = (_Float16)w1.z; pb.h[7] = (_Float16)w1.w;
      *reinterpret_cast<uint4*>(&Bs[eo]) = pb.u;
    }
    __syncthreads();   // drains vmcnt + lgkmcnt

#pragma unroll
    for (int kk = 0; kk < 4; ++kk) {
      f16x8 af[2], bf[2];
#pragma unroll
      for (int f = 0; f < 2; ++f) {
        const int arow = wr * 32 + f * 16 + (lane & 15);
        const int ac   = (kk * 4 + (lane >> 4)) ^ (arow & 7);
        af[f] = *reinterpret_cast<f16x8*>(&As[arow * 128 + ac * 8]);
        const int brow = wc * 32 + f * 16 + (lane & 15);
        const int bc   = (kk * 4 + (lane >> 4)) ^ (brow & 7);
        bf[f] = *reinterpret_cast<f16x8*>(&Bs[brow * 128 + bc * 8]);
      }
#pragma unroll
      for (int fr = 0; fr < 2; ++fr)
#pragma unroll
        for (int fc = 0; fc < 2; ++fc)
          acc[fr][fc] = __builtin_amdgcn_mfma_f32_16x16x32_f16(af[fr], bf[fc], acc[fr][fc], 0, 0, 0);
    }
    __syncthreads();
  }

  // ---- epilogue: acc+bias -> f32 LDS tile [64][64] (in As, 16 KB), then
  //      coalesced float4 Q-load + add + float4 store ----
  {
    const int col = lane & 15;
    const int rg4 = lane >> 4;
    float bias2[2];
    bias2[0] = bout[nb + wc * 32 + 0 * 16 + col];
    bias2[1] = bout[nb + wc * 32 + 1 * 16 + col];
    float* Ep = reinterpret_cast<float*>(As);   // [64][64] f32 = 16 KB exact
#pragma unroll
    for (int fr = 0; fr < 2; ++fr)
#pragma unroll
      for (int fc = 0; fc < 2; ++fc)
#pragma unroll
        for (int j = 0; j < 4; ++j)
          Ep[(wr * 32 + fr * 16 + rg4 * 4 + j) * 64 + wc * 32 + fc * 16 + col] =
              acc[fr][fc][j] + bias2[fc];
    __syncthreads();

    // 64 rows x 16 chunks(16B) = 1024 chunks; thread handles 4
#pragma unroll
    for (int i = 0; i < 4; ++i) {
      const int g   = i * 256 + t;
      const int row = g >> 4;
      const int ch  = g & 15;
      const int m   = mb + row;
      if (m < M_TOTAL) {
        const int n0 = nb + ch * 4;
        float4 v = *reinterpret_cast<const float4*>(&Ep[row * 64 + ch * 4]);
        const float4 q4 = *reinterpret_cast<const float4*>(Q + (size_t)m * EMB + n0);
        v.x += q4.x; v.y += q4.y; v.z += q4.z; v.w += q4.w;
        *reinterpret_cast<float4*>(out + (size_t)m * EMB + n0) = v;
      }
    }
  }
}

extern "C" void kernel_launch(void* const* d_in, const int* in_sizes, int n_in,
                              void* d_out, int out_size, void* d_ws, size_t ws_size,
                              hipStream_t stream) {
  const float* Q     = (const float*)d_in[0];
  const float* refp  = (const float*)d_in[1];
  const float* Wv    = (const float*)d_in[3];
  const float* bv    = (const float*)d_in[4];
  const float* Woff  = (const float*)d_in[5];
  const float* boff  = (const float*)d_in[6];
  const float* Wattn = (const float*)d_in[7];
  const float* battn = (const float*)d_in[8];
  const float* Wout  = (const float*)d_in[9];
  const float* bout  = (const float*)d_in[10];
  float* out = (float*)d_out;

  if (ws_size < WS_NEED2) return;

  unsigned short* valH  = (unsigned short*)((char*)d_ws + WS_VAL_OFF);
  unsigned short* offH  = (unsigned short*)((char*)d_ws + WS_OFFW_OFF);
  unsigned short* attH  = (unsigned short*)((char*)d_ws + WS_ATT_OFF);
  unsigned short* sampH = (unsigned short*)((char*)d_ws + WS_SAMP_OFF);
  _Float16*       WH    = (_Float16*)((char*)d_ws + WS_WH_OFF);   // overlays sampH

  const int nblk_q8 = (M_TOTAL + QB - 1) / QB;   // 4456

  k_prep<<<dim3(80), dim3(256), 0, stream>>>(Wv, Woff, Wattn, WH);
  k_gemm1<<<dim3(MTILES * 2), dim3(256), 0, stream>>>(Q, WH, bv, boff, battn,
                                                      valH, offH, attH);
  k_gather<<<dim3(nblk_q8), dim3(256), 0, stream>>>(refp, valH, offH, attH, sampH);
  k_gemm2<<<dim3(MTILES * 4), dim3(256), 0, stream>>>(Q, sampH, Wout, bout, out);
}